// Round 6
// baseline (212.773 us; speedup 1.0000x reference)
//
#include <hip/hip_runtime.h>
#include <math.h>

#define NPTS 16384
#define KN 32
#define C 256
#define NQ 8192              // 8 * 1024 queries
#define PF_ELEMS (NQ * C)

#define W1P_ELEMS (3 * 16 * 64 * 8)                 // 24576  (Ktiles=3, Ntiles=16)
#define W2P_ELEMS (8 * 16 * 64 * 8)                 // 65536  (Ktiles=8)
#define HSTR 264                                    // halves per H16 row

typedef _Float16 half8 __attribute__((ext_vector_type(8)));
typedef _Float16 half4v __attribute__((ext_vector_type(4)));
typedef float f32x4 __attribute__((ext_vector_type(4)));

// ---------------------------------------------------------------------------
// Pack W1 (91x256, K-padded to 96) and W2 (256x256) into f16 B-fragment order
// for mfma_f32_16x16x32_f16 (layout verified in round 2):
//   flat = ((ktile*16 + ntile)*64 + lane)*8 + j
//   k = ktile*32 + (lane>>4)*8 + j ;  n = ntile*16 + (lane&15)
// ---------------------------------------------------------------------------
__global__ void prep_w_kernel(const float* __restrict__ W1,
                              const float* __restrict__ W2,
                              _Float16* __restrict__ wp) {
    const int e = blockIdx.x * 256 + threadIdx.x;
    if (e < W1P_ELEMS) {
        const int j = e & 7, lane = (e >> 3) & 63, nt = (e >> 9) & 15, kt = e >> 13;
        const int k = kt * 32 + (lane >> 4) * 8 + j;
        const int n = nt * 16 + (lane & 15);
        wp[e] = (_Float16)((k < 91) ? W1[k * C + n] : 0.0f);
    } else {
        const int e2 = e - W1P_ELEMS;
        const int j = e2 & 7, lane = (e2 >> 3) & 63, nt = (e2 >> 9) & 15, kt = e2 >> 13;
        const int k = kt * 32 + (lane >> 4) * 8 + j;
        const int n = nt * 16 + (lane & 15);
        wp[e] = (_Float16)W2[k * C + n];
    }
}

// tanh-approx GeLU: max err ~3e-4.  y = x - x/(e^{2u}+1)
__device__ __forceinline__ float gelu_tanh(float x) {
    const float t  = x * x;
    const float p2 = fmaf(t, 0.0713548162726f, 1.59576912161f);
    const float e  = __expf(x * p2);
    return x - x * __builtin_amdgcn_rcpf(e + 1.0f);
}

// ---------------------------------------------------------------------------
// Fused: ball-query + gather/posenc + MLP1(LN,GeLU) + MLP2(LN) + max.
// Round-6: register-resident LN epilogues (stats via shfl tree + 1.5KB LDS
// combine), XOR-swizzled H16 chunks (conflict-free C-stores), LN2/max never
// stored to LDS. All private-array indices compile-time (round-3 lesson).
// ---------------------------------------------------------------------------
__global__ void __launch_bounds__(256, 5)
encoder_fused(const float* __restrict__ xyz,
              const float* __restrict__ pf,
              const float* __restrict__ ctr,
              const float* __restrict__ b1, const float* __restrict__ g1,
              const float* __restrict__ be1,
              const float* __restrict__ b2, const float* __restrict__ g2,
              const float* __restrict__ be2,
              const _Float16* __restrict__ w1p,
              const _Float16* __restrict__ w2p,
              float* __restrict__ out0,      // patch_feature [8192][256]
              float* __restrict__ out1) {    // neighbor idx as float [8192][32]
    const int q = blockIdx.x;
    const int b = q >> 10;
    const int t = threadIdx.x;
    const int w = t >> 6;
    const int lane = t & 63;
    const int quad = lane >> 4;
    const int l15  = lane & 15;

    // H16: f16 activation buffer; 16B chunks XOR-swizzled by (row>>2)&3:
    //   phys_col = col ^ (((row>>2)&3)<<3)
    __shared__ __align__(16) unsigned char H16raw[KN * HSTR * 2];  // 16896
    __shared__ __align__(16) unsigned char Xsraw[KN * 104 * 2];    // 6656
    __shared__ float lnp[4 * 256];                                  // g1,be1,g2,be2
    __shared__ __align__(16) float sums[KN][12];   // per-row {s,s2} per wave
    __shared__ int nbr[KN];
    __shared__ int wcnt[2][4];

    _Float16 (*H16)[HSTR] = (_Float16(*)[HSTR])H16raw;
    _Float16 (*Xs)[104]   = (_Float16(*)[104])Xsraw;
    float* lng1  = lnp;        float* lnbe1 = lnp + 256;
    float* lng2  = lnp + 512;  float* lnbe2 = lnp + 768;

    lnp[t]       = g1[t];  lnp[256 + t] = be1[t];
    lnp[512 + t] = g2[t];  lnp[768 + t] = be2[t];

    // ---- Phase 0: ball query (block-wide ordered compaction) ----
    // first-32-ascending == reference sort+slice; exact unfused fp32 formula.
    const float* xb = xyz + (size_t)b * NPTS * 3;
    const float cx = ctr[q * 3 + 0];
    const float cy = ctr[q * 3 + 1];
    const float cz = ctr[q * 3 + 2];
    const float sc = __fadd_rn(__fadd_rn(__fmul_rn(cx, cx), __fmul_rn(cy, cy)),
                               __fmul_rn(cz, cz));

    int found = 0;
    int par = 0;
    for (int base = 0; base < NPTS; base += 256) {
        const int n = base + t;
        const float px = xb[n * 3 + 0];
        const float py = xb[n * 3 + 1];
        const float pz = xb[n * 3 + 2];
        const float sp = __fadd_rn(__fadd_rn(__fmul_rn(px, px), __fmul_rn(py, py)),
                                   __fmul_rn(pz, pz));
        const float dt = __fadd_rn(__fadd_rn(__fmul_rn(cx, px), __fmul_rn(cy, py)),
                                   __fmul_rn(cz, pz));
        const float sqr = __fsub_rn(__fadd_rn(sc, sp), __fmul_rn(2.0f, dt));
        const bool inball = (sqr <= 0.0625f);

        const unsigned long long m = __ballot(inball);
        if (lane == 0) wcnt[par][w] = (int)__popcll(m);
        __syncthreads();
        int pre = found;
        if (w > 0) pre += wcnt[par][0];
        if (w > 1) pre += wcnt[par][1];
        if (w > 2) pre += wcnt[par][2];
        const int tot = found + wcnt[par][0] + wcnt[par][1] + wcnt[par][2] + wcnt[par][3];
        const int pos = pre + (int)__popcll(m & ((1ull << lane) - 1ull));
        if (inball && pos < KN) nbr[pos] = n;
        found = tot;                  // block-uniform
        par ^= 1;
        if (found >= KN) break;
    }
    __syncthreads();                  // nbr visible to all
    const int count = (found < KN) ? found : KN;
    const int first = (count > 0) ? nbr[0] : NPTS;

    if (t < KN)
        out1[(size_t)q * KN + t] = (float)((t < count) ? nbr[t] : first);

    // ---- Phase 1: gather + rel + posenc into Xs (f16, K-padded to 96) ----
    {
        const int k  = t >> 3;
        const int tc = t & 7;
        const int nidx = (k < count) ? nbr[k] : first;
        const int n = (nidx < NPTS) ? nidx : NPTS - 1;   // JAX OOB gather clamp
        const float rx = xb[n * 3 + 0] - cx;
        const float ry = xb[n * 3 + 1] - cy;
        const float rz = xb[n * 3 + 2] - cz;
        const float* pfr = pf + ((size_t)b * NPTS + n) * 64;

        const float4 f0 = *(const float4*)(pfr + tc * 8);
        const float4 f1 = *(const float4*)(pfr + tc * 8 + 4);
        half8 hv;
        hv[0] = (_Float16)f0.x; hv[1] = (_Float16)f0.y;
        hv[2] = (_Float16)f0.z; hv[3] = (_Float16)f0.w;
        hv[4] = (_Float16)f1.x; hv[5] = (_Float16)f1.y;
        hv[6] = (_Float16)f1.z; hv[7] = (_Float16)f1.w;
        *(half8*)&Xs[k][tc * 8] = hv;

        half4v ov;
        #pragma unroll
        for (int j = 0; j < 4; ++j) {
            const int c = 64 + tc * 4 + j;
            float v;
            if (c < 67) {
                v = (c == 64) ? rx : ((c == 65) ? ry : rz);
            } else if (c < 91) {
                const int jj = c - 67;
                const int d = jj >> 3;
                const int mm = jj & 7;
                const float f = (float)(1 << (mm & 3));
                const float r = (d == 0) ? rx : ((d == 1) ? ry : rz);
                v = (mm < 4) ? __sinf(r * f) : __cosf(r * f);
            } else {
                v = 0.0f;
            }
            ov[j] = (_Float16)v;
        }
        *(half4v*)&Xs[k][64 + tc * 4] = ov;
    }
    __syncthreads();

    const int qx = (quad ^ (l15 >> 2)) * 8;   // swizzled chunk offset (A-reads)

    f32x4 acc[2][4];

    // ---- Phase 2: GEMM1  X[32x96] @ W1[96x256] ----
    #pragma unroll
    for (int mt = 0; mt < 2; ++mt)
        #pragma unroll
        for (int nt = 0; nt < 4; ++nt)
            acc[mt][nt] = (f32x4){0.f, 0.f, 0.f, 0.f};

    #pragma unroll
    for (int kt = 0; kt < 3; ++kt) {
        const half8 a0 = *(const half8*)&Xs[l15][kt * 32 + quad * 8];
        const half8 a1 = *(const half8*)&Xs[16 + l15][kt * 32 + quad * 8];
        #pragma unroll
        for (int nt = 0; nt < 4; ++nt) {
            const int ntg = w * 4 + nt;
            const half8 bf = *(const half8*)&w1p[((kt * 16 + ntg) * 64 + lane) * 8];
            acc[0][nt] = __builtin_amdgcn_mfma_f32_16x16x32_f16(a0, bf, acc[0][nt], 0, 0, 0);
            acc[1][nt] = __builtin_amdgcn_mfma_f32_16x16x32_f16(a1, bf, acc[1][nt], 0, 0, 0);
        }
    }

    // ---- LN1 epilogue: bias + stats(reg) + combine + GeLU + swizzled store ----
    {
        #pragma unroll
        for (int nt = 0; nt < 4; ++nt) {
            const float bb = b1[w * 64 + nt * 16 + l15];
            #pragma unroll
            for (int mt = 0; mt < 2; ++mt)
                #pragma unroll
                for (int r = 0; r < 4; ++r)
                    acc[mt][nt][r] += bb;
        }
        float s[2][4], z[2][4];
        #pragma unroll
        for (int mt = 0; mt < 2; ++mt)
            #pragma unroll
            for (int r = 0; r < 4; ++r) {
                const float a = acc[mt][0][r], bb = acc[mt][1][r];
                const float c = acc[mt][2][r], d = acc[mt][3][r];
                s[mt][r] = (a + bb) + (c + d);
                z[mt][r] = fmaf(a, a, fmaf(bb, bb, fmaf(c, c, d * d)));
            }
        #pragma unroll
        for (int off = 1; off < 16; off <<= 1) {
            #pragma unroll
            for (int mt = 0; mt < 2; ++mt)
                #pragma unroll
                for (int r = 0; r < 4; ++r) {
                    s[mt][r] += __shfl_xor(s[mt][r], off, 64);
                    z[mt][r] += __shfl_xor(z[mt][r], off, 64);
                }
        }
        if (l15 == 0) {
            #pragma unroll
            for (int mt = 0; mt < 2; ++mt)
                #pragma unroll
                for (int r = 0; r < 4; ++r) {
                    const int row = 16 * mt + 4 * quad + r;
                    float2 v; v.x = s[mt][r]; v.y = z[mt][r];
                    *(float2*)&sums[row][2 * w] = v;
                }
        }
        __syncthreads();
        float mu[2][4], rs[2][4];
        #pragma unroll
        for (int mt = 0; mt < 2; ++mt)
            #pragma unroll
            for (int r = 0; r < 4; ++r) {
                const int row = 16 * mt + 4 * quad + r;
                const f32x4 v0 = *(const f32x4*)&sums[row][0];
                const f32x4 v1 = *(const f32x4*)&sums[row][4];
                const float ss = (v0.x + v0.z) + (v1.x + v1.z);
                const float qq = (v0.y + v0.w) + (v1.y + v1.w);
                const float m  = ss * (1.0f / 256.0f);
                const float va = fmaf(qq, 1.0f / 256.0f, -m * m);
                mu[mt][r] = m;
                rs[mt][r] = __builtin_amdgcn_rsqf(va + 1e-5f);
            }
        #pragma unroll
        for (int nt = 0; nt < 4; ++nt) {
            const int col  = w * 64 + nt * 16 + l15;
            const int colp = col ^ (quad << 3);          // swizzled store col
            const float g  = lng1[col];
            const float be = lnbe1[col];
            #pragma unroll
            for (int mt = 0; mt < 2; ++mt)
                #pragma unroll
                for (int r = 0; r < 4; ++r) {
                    const float y = fmaf((acc[mt][nt][r] - mu[mt][r]) * rs[mt][r], g, be);
                    H16[16 * mt + 4 * quad + r][colp] = (_Float16)gelu_tanh(y);
                }
        }
    }
    __syncthreads();

    // ---- Phase 4: GEMM2  H[32x256] @ W2[256x256] (swizzled A-reads) ----
    #pragma unroll
    for (int mt = 0; mt < 2; ++mt)
        #pragma unroll
        for (int nt = 0; nt < 4; ++nt)
            acc[mt][nt] = (f32x4){0.f, 0.f, 0.f, 0.f};

    #pragma unroll
    for (int kt = 0; kt < 8; ++kt) {
        const half8 a0 = *(const half8*)&H16[l15][kt * 32 + qx];
        const half8 a1 = *(const half8*)&H16[16 + l15][kt * 32 + qx];
        #pragma unroll
        for (int nt = 0; nt < 4; ++nt) {
            const int ntg = w * 4 + nt;
            const half8 bf = *(const half8*)&w2p[((kt * 16 + ntg) * 64 + lane) * 8];
            acc[0][nt] = __builtin_amdgcn_mfma_f32_16x16x32_f16(a0, bf, acc[0][nt], 0, 0, 0);
            acc[1][nt] = __builtin_amdgcn_mfma_f32_16x16x32_f16(a1, bf, acc[1][nt], 0, 0, 0);
        }
    }

    // ---- LN2 epilogue: bias + stats + max(reg) + global store (no LDS H2) ----
    {
        #pragma unroll
        for (int nt = 0; nt < 4; ++nt) {
            const float bb = b2[w * 64 + nt * 16 + l15];
            #pragma unroll
            for (int mt = 0; mt < 2; ++mt)
                #pragma unroll
                for (int r = 0; r < 4; ++r)
                    acc[mt][nt][r] += bb;
        }
        float s[2][4], z[2][4];
        #pragma unroll
        for (int mt = 0; mt < 2; ++mt)
            #pragma unroll
            for (int r = 0; r < 4; ++r) {
                const float a = acc[mt][0][r], bb = acc[mt][1][r];
                const float c = acc[mt][2][r], d = acc[mt][3][r];
                s[mt][r] = (a + bb) + (c + d);
                z[mt][r] = fmaf(a, a, fmaf(bb, bb, fmaf(c, c, d * d)));
            }
        #pragma unroll
        for (int off = 1; off < 16; off <<= 1) {
            #pragma unroll
            for (int mt = 0; mt < 2; ++mt)
                #pragma unroll
                for (int r = 0; r < 4; ++r) {
                    s[mt][r] += __shfl_xor(s[mt][r], off, 64);
                    z[mt][r] += __shfl_xor(z[mt][r], off, 64);
                }
        }
        if (l15 == 0) {
            #pragma unroll
            for (int mt = 0; mt < 2; ++mt)
                #pragma unroll
                for (int r = 0; r < 4; ++r) {
                    const int row = 16 * mt + 4 * quad + r;
                    float2 v; v.x = s[mt][r]; v.y = z[mt][r];
                    *(float2*)&sums[row][2 * w] = v;
                }
        }
        __syncthreads();
        float mu[2][4], rs[2][4];
        #pragma unroll
        for (int mt = 0; mt < 2; ++mt)
            #pragma unroll
            for (int r = 0; r < 4; ++r) {
                const int row = 16 * mt + 4 * quad + r;
                const f32x4 v0 = *(const f32x4*)&sums[row][0];
                const f32x4 v1 = *(const f32x4*)&sums[row][4];
                const float ss = (v0.x + v0.z) + (v1.x + v1.z);
                const float qq = (v0.y + v0.w) + (v1.y + v1.w);
                const float m  = ss * (1.0f / 256.0f);
                const float va = fmaf(qq, 1.0f / 256.0f, -m * m);
                mu[mt][r] = m;
                rs[mt][r] = __builtin_amdgcn_rsqf(va + 1e-5f);
            }
        #pragma unroll
        for (int nt = 0; nt < 4; ++nt) {
            const int col  = w * 64 + nt * 16 + l15;
            const float g  = lng2[col];
            const float be = lnbe2[col];
            float mx = -INFINITY;
            #pragma unroll
            for (int mt = 0; mt < 2; ++mt)
                #pragma unroll
                for (int r = 0; r < 4; ++r) {
                    const float y = fmaf((acc[mt][nt][r] - mu[mt][r]) * rs[mt][r], g, be);
                    mx = fmaxf(mx, y);
                }
            mx = fmaxf(mx, __shfl_xor(mx, 16, 64));
            mx = fmaxf(mx, __shfl_xor(mx, 32, 64));
            if (quad == 0)
                out0[(size_t)q * C + col] = mx;
        }
    }
}

extern "C" void kernel_launch(void* const* d_in, const int* in_sizes, int n_in,
                              void* d_out, int out_size, void* d_ws, size_t ws_size,
                              hipStream_t stream) {
    const float* xyz = (const float*)d_in[0];
    const float* pf  = (const float*)d_in[1];
    const float* ctr = (const float*)d_in[2];
    const float* W1  = (const float*)d_in[3];
    const float* b1  = (const float*)d_in[4];
    const float* g1  = (const float*)d_in[5];
    const float* be1 = (const float*)d_in[6];
    const float* W2  = (const float*)d_in[7];
    const float* b2  = (const float*)d_in[8];
    const float* g2  = (const float*)d_in[9];
    const float* be2 = (const float*)d_in[10];

    float* out = (float*)d_out;
    _Float16* wp = (_Float16*)d_ws;

    prep_w_kernel<<<(W1P_ELEMS + W2P_ELEMS) / 256, 256, 0, stream>>>(W1, W2, wp);
    encoder_fused<<<NQ, 256, 0, stream>>>(xyz, pf, ctr,
                                          b1, g1, be1, b2, g2, be2,
                                          wp, wp + W1P_ELEMS,
                                          out, out + PF_ELEMS);
}

// Round 8
// 191.206 us; speedup vs baseline: 1.1128x; 1.1128x over previous
//
#include <hip/hip_runtime.h>
#include <math.h>

#define NPTS 16384
#define KN 32
#define C 256
#define NQ 8192              // 8 * 1024 queries
#define PF_ELEMS (NQ * C)

#define W1P_ELEMS (3 * 16 * 64 * 8)                 // 24576  (Ktiles=3, Ntiles=16)
#define W2P_ELEMS (8 * 16 * 64 * 8)                 // 65536  (Ktiles=8)
#define HSTR 264                                    // halves per H16 row

typedef _Float16 half8 __attribute__((ext_vector_type(8)));
typedef _Float16 half4v __attribute__((ext_vector_type(4)));
typedef _Float16 half2t __attribute__((ext_vector_type(2)));
typedef float f32x4 __attribute__((ext_vector_type(4)));

union H8u { half8 v; half2t h2[4]; };

__device__ __forceinline__ float fdot2f(half2t a, half2t b, float c) {
#if __has_builtin(__builtin_amdgcn_fdot2)
    return __builtin_amdgcn_fdot2(a, b, c, false);
#else
    return fmaf((float)a[1], (float)b[1], fmaf((float)a[0], (float)b[0], c));
#endif
}

// tanh-approx GeLU: max err ~3e-4.  y = x - x/(e^{2u}+1)
__device__ __forceinline__ float gelu_tanh(float x) {
    const float t  = x * x;
    const float p2 = fmaf(t, 0.0713548162726f, 1.59576912161f);
    const float e  = __expf(x * p2);
    return x - x * __builtin_amdgcn_rcpf(e + 1.0f);
}

__device__ __forceinline__ void stat8(const H8u& u, half2t ones, float& s, float& s2) {
    #pragma unroll
    for (int j = 0; j < 4; ++j) {
        s  = fdot2f(u.h2[j], ones, s);
        s2 = fdot2f(u.h2[j], u.h2[j], s2);
    }
}

__device__ __forceinline__ void norm_gelu8(H8u& u, const H8u& g, const H8u& be,
                                           half2t rsh, half2t nmuh) {
    #pragma unroll
    for (int j = 0; j < 4; ++j) {
        const half2t A = g.h2[j] * rsh;
        const half2t B = A * nmuh + be.h2[j];
        const half2t y = u.h2[j] * A + B;
        half2t o;
        o[0] = (_Float16)gelu_tanh((float)y[0]);
        o[1] = (_Float16)gelu_tanh((float)y[1]);
        u.h2[j] = o;
    }
}

__device__ __forceinline__ void norm8(H8u& u, const H8u& g, const H8u& be,
                                      half2t rsh, half2t nmuh) {
    #pragma unroll
    for (int j = 0; j < 4; ++j) {
        const half2t A = g.h2[j] * rsh;
        const half2t B = A * nmuh + be.h2[j];
        u.h2[j] = u.h2[j] * A + B;
    }
}

// ---------------------------------------------------------------------------
// Pack W1 (91x256, K-padded to 96) and W2 (256x256) into f16 B-fragment order
// (layout verified round 2). Coalesced source reads; scattered b16 writes.
//   k = kt*32 + quad*8 + j ; n = nt*16 + l15 ; lane = quad*16 + l15
//   flat = ((kt*16 + nt)*64 + lane)*8 + j
// ---------------------------------------------------------------------------
__global__ void prep_w_kernel(const float* __restrict__ W1,
                              const float* __restrict__ W2,
                              _Float16* __restrict__ wp) {
    const int idx = blockIdx.x * 256 + threadIdx.x;   // 0 .. 90111
    if (idx < 96 * 256) {
        const int k = idx >> 8, n = idx & 255;
        const float v = (k < 91) ? W1[k * 256 + n] : 0.0f;
        const int kt = k >> 5, quad = (k >> 3) & 3, j = k & 7;
        const int nt = n >> 4, l15 = n & 15;
        wp[(((kt * 16 + nt) * 64) + quad * 16 + l15) * 8 + j] = (_Float16)v;
    } else {
        const int e = idx - 96 * 256;
        const int k = e >> 8, n = e & 255;
        const int kt = k >> 5, quad = (k >> 3) & 3, j = k & 7;
        const int nt = n >> 4, l15 = n & 15;
        wp[W1P_ELEMS + (((kt * 16 + nt) * 64) + quad * 16 + l15) * 8 + j] =
            (_Float16)W2[k * 256 + n];
    }
}

// ---------------------------------------------------------------------------
// Fused: ball-query + gather/posenc + MLP1(LN,GeLU) + MLP2(LN) + max.
// Round-8 (= round-7 fixed): round-5 skeleton (thread-owns-row-slice LN via
// LDS) + XOR-swizzled H16 chunks (phys_chunk = chunk ^ ((row>>2)&3), kills
// C-store 4-way conflicts, verified round 6) + fdot2 stats + packed-f16
// normalize + f16 LN params (LDS 25.8 KB -> 6 blocks/CU).
// No runtime-indexed private arrays (round-3 lesson).
// ---------------------------------------------------------------------------
__global__ void __launch_bounds__(256, 6)
encoder_fused(const float* __restrict__ xyz,
              const float* __restrict__ pf,
              const float* __restrict__ ctr,
              const float* __restrict__ b1, const float* __restrict__ g1,
              const float* __restrict__ be1,
              const float* __restrict__ b2, const float* __restrict__ g2,
              const float* __restrict__ be2,
              const _Float16* __restrict__ w1p,
              const _Float16* __restrict__ w2p,
              float* __restrict__ out0,      // patch_feature [8192][256]
              float* __restrict__ out1) {    // neighbor idx as float [8192][32]
    const int q = blockIdx.x;
    const int b = q >> 10;
    const int t = threadIdx.x;
    const int w = t >> 6;
    const int lane = t & 63;
    const int quad = lane >> 4;
    const int l15  = lane & 15;

    __shared__ __align__(16) unsigned char H16raw[KN * HSTR * 2];  // 16896
    __shared__ __align__(16) unsigned char Xsraw[KN * 104 * 2];    // 6656
    __shared__ __align__(16) _Float16 lnph[4 * 256];               // 2048: g1,be1,g2,be2
    __shared__ int nbr[KN];
    __shared__ int wcnt[2][4];

    _Float16 (*H16)[HSTR] = (_Float16(*)[HSTR])H16raw;
    _Float16 (*Xs)[104]   = (_Float16(*)[104])Xsraw;
    _Float16* g1h  = lnph;
    _Float16* be1h = lnph + 256;
    _Float16* g2h  = lnph + 512;
    _Float16* be2h = lnph + 768;

    lnph[t]       = (_Float16)g1[t];
    lnph[256 + t] = (_Float16)be1[t];
    lnph[512 + t] = (_Float16)g2[t];
    lnph[768 + t] = (_Float16)be2[t];

    // ---- Phase 0: ball query (block-wide ordered compaction) ----
    // first-32-ascending == reference sort+slice; exact unfused fp32 formula.
    const float* xb = xyz + (size_t)b * NPTS * 3;
    const float cx = ctr[q * 3 + 0];
    const float cy = ctr[q * 3 + 1];
    const float cz = ctr[q * 3 + 2];
    const float sc = __fadd_rn(__fadd_rn(__fmul_rn(cx, cx), __fmul_rn(cy, cy)),
                               __fmul_rn(cz, cz));

    int found = 0;
    int par = 0;
    for (int base = 0; base < NPTS; base += 256) {
        const int n = base + t;
        const float px = xb[n * 3 + 0];
        const float py = xb[n * 3 + 1];
        const float pz = xb[n * 3 + 2];
        const float sp = __fadd_rn(__fadd_rn(__fmul_rn(px, px), __fmul_rn(py, py)),
                                   __fmul_rn(pz, pz));
        const float dt = __fadd_rn(__fadd_rn(__fmul_rn(cx, px), __fmul_rn(cy, py)),
                                   __fmul_rn(cz, pz));
        const float sqr = __fsub_rn(__fadd_rn(sc, sp), __fmul_rn(2.0f, dt));
        const bool inball = (sqr <= 0.0625f);

        const unsigned long long m = __ballot(inball);
        if (lane == 0) wcnt[par][w] = (int)__popcll(m);
        __syncthreads();
        int pre = found;
        if (w > 0) pre += wcnt[par][0];
        if (w > 1) pre += wcnt[par][1];
        if (w > 2) pre += wcnt[par][2];
        const int tot = found + wcnt[par][0] + wcnt[par][1] + wcnt[par][2] + wcnt[par][3];
        const int pos = pre + (int)__popcll(m & ((1ull << lane) - 1ull));
        if (inball && pos < KN) nbr[pos] = n;
        found = tot;                  // block-uniform
        par ^= 1;
        if (found >= KN) break;
    }
    __syncthreads();                  // nbr visible to all
    const int count = (found < KN) ? found : KN;
    const int first = (count > 0) ? nbr[0] : NPTS;

    if (t < KN)
        out1[(size_t)q * KN + t] = (float)((t < count) ? nbr[t] : first);

    // ---- Phase 1: gather + rel + posenc into Xs (f16, K-padded to 96) ----
    {
        const int k  = t >> 3;
        const int tc = t & 7;
        const int nidx = (k < count) ? nbr[k] : first;
        const int n = (nidx < NPTS) ? nidx : NPTS - 1;   // JAX OOB gather clamp
        const float rx = xb[n * 3 + 0] - cx;
        const float ry = xb[n * 3 + 1] - cy;
        const float rz = xb[n * 3 + 2] - cz;
        const float* pfr = pf + ((size_t)b * NPTS + n) * 64;

        const float4 f0 = *(const float4*)(pfr + tc * 8);
        const float4 f1 = *(const float4*)(pfr + tc * 8 + 4);
        half8 hv;
        hv[0] = (_Float16)f0.x; hv[1] = (_Float16)f0.y;
        hv[2] = (_Float16)f0.z; hv[3] = (_Float16)f0.w;
        hv[4] = (_Float16)f1.x; hv[5] = (_Float16)f1.y;
        hv[6] = (_Float16)f1.z; hv[7] = (_Float16)f1.w;
        *(half8*)&Xs[k][tc * 8] = hv;

        half4v ov;
        #pragma unroll
        for (int j = 0; j < 4; ++j) {
            const int c = 64 + tc * 4 + j;
            float v;
            if (c < 67) {
                v = (c == 64) ? rx : ((c == 65) ? ry : rz);
            } else if (c < 91) {
                const int jj = c - 67;
                const int d = jj >> 3;
                const int mm = jj & 7;
                const float f = (float)(1 << (mm & 3));
                const float r = (d == 0) ? rx : ((d == 1) ? ry : rz);
                v = (mm < 4) ? __sinf(r * f) : __cosf(r * f);
            } else {
                v = 0.0f;
            }
            ov[j] = (_Float16)v;
        }
        *(half4v*)&Xs[k][64 + tc * 4] = ov;
    }
    __syncthreads();

    const int qx = (quad ^ (l15 >> 2)) * 8;   // swizzled chunk (GEMM2 A-reads)

    f32x4 acc[2][4];

    // ---- Phase 2: GEMM1  X[32x96] @ W1[96x256] -> H16 (+b1, swizzled) ----
    #pragma unroll
    for (int mt = 0; mt < 2; ++mt)
        #pragma unroll
        for (int nt = 0; nt < 4; ++nt)
            acc[mt][nt] = (f32x4){0.f, 0.f, 0.f, 0.f};

    #pragma unroll
    for (int kt = 0; kt < 3; ++kt) {
        const half8 a0 = *(const half8*)&Xs[l15][kt * 32 + quad * 8];
        const half8 a1 = *(const half8*)&Xs[16 + l15][kt * 32 + quad * 8];
        #pragma unroll
        for (int nt = 0; nt < 4; ++nt) {
            const int ntg = w * 4 + nt;
            const half8 bf = *(const half8*)&w1p[((kt * 16 + ntg) * 64 + lane) * 8];
            acc[0][nt] = __builtin_amdgcn_mfma_f32_16x16x32_f16(a0, bf, acc[0][nt], 0, 0, 0);
            acc[1][nt] = __builtin_amdgcn_mfma_f32_16x16x32_f16(a1, bf, acc[1][nt], 0, 0, 0);
        }
    }
    #pragma unroll
    for (int nt = 0; nt < 4; ++nt) {
        const int col  = w * 64 + nt * 16 + l15;
        const int colp = col ^ (quad << 3);          // swizzled store col
        const float bb = b1[col];
        #pragma unroll
        for (int mt = 0; mt < 2; ++mt)
            #pragma unroll
            for (int r = 0; r < 4; ++r)
                H16[16 * mt + 4 * quad + r][colp] = (_Float16)(acc[mt][nt][r] + bb);
    }
    __syncthreads();

    const int row  = t >> 3;        // LN ownership: thread = (row, octet p)
    const int p    = t & 7;         // owns cols [16p,16p+16) and [128+16p,+16)
    const int qrow = (row >> 2) & 3;
    _Float16* hb = &H16[row][0];
    const int a0o = (( 2 * p    ) ^ qrow) << 3;   // phys chunk offsets (halves)
    const int a1o = (( 2 * p + 1) ^ qrow) << 3;
    const int a2o = ((16 + 2 * p) ^ qrow) << 3;
    const int a3o = ((17 + 2 * p) ^ qrow) << 3;
    half2t ones;
    ones[0] = (_Float16)1.0f;
    ones[1] = (_Float16)1.0f;

    // ---- Phase 3: LN1 + GeLU, in place on H16 ----
    {
        H8u u0, u1, u2, u3;
        u0.v = *(const half8*)(hb + a0o);
        u1.v = *(const half8*)(hb + a1o);
        u2.v = *(const half8*)(hb + a2o);
        u3.v = *(const half8*)(hb + a3o);

        float s = 0.0f, s2 = 0.0f;
        stat8(u0, ones, s, s2); stat8(u1, ones, s, s2);
        stat8(u2, ones, s, s2); stat8(u3, ones, s, s2);
        #pragma unroll
        for (int off = 1; off < 8; off <<= 1) {
            s  += __shfl_xor(s, off, 64);
            s2 += __shfl_xor(s2, off, 64);
        }
        const float mu  = s * (1.0f / 256.0f);
        const float var = fmaf(s2, 1.0f / 256.0f, -mu * mu);
        const float rs  = __builtin_amdgcn_rsqf(var + 1e-5f);
        half2t rsh, nmuh;
        rsh[0]  = (_Float16)rs;    rsh[1]  = (_Float16)rs;
        nmuh[0] = (_Float16)(-mu); nmuh[1] = (_Float16)(-mu);

        H8u gA0, gA1, gB0, gB1, bA0, bA1, bB0, bB1;
        gA0.v = *(const half8*)&g1h[16 * p];        bA0.v = *(const half8*)&be1h[16 * p];
        gA1.v = *(const half8*)&g1h[16 * p + 8];    bA1.v = *(const half8*)&be1h[16 * p + 8];
        gB0.v = *(const half8*)&g1h[128 + 16 * p];  bB0.v = *(const half8*)&be1h[128 + 16 * p];
        gB1.v = *(const half8*)&g1h[136 + 16 * p];  bB1.v = *(const half8*)&be1h[136 + 16 * p];

        norm_gelu8(u0, gA0, bA0, rsh, nmuh);
        norm_gelu8(u1, gA1, bA1, rsh, nmuh);
        norm_gelu8(u2, gB0, bB0, rsh, nmuh);
        norm_gelu8(u3, gB1, bB1, rsh, nmuh);

        *(half8*)(hb + a0o) = u0.v;
        *(half8*)(hb + a1o) = u1.v;
        *(half8*)(hb + a2o) = u2.v;
        *(half8*)(hb + a3o) = u3.v;
    }
    __syncthreads();

    // ---- Phase 4: GEMM2  H[32x256] @ W2[256x256] -> H16 in place (+b2) ----
    #pragma unroll
    for (int mt = 0; mt < 2; ++mt)
        #pragma unroll
        for (int nt = 0; nt < 4; ++nt)
            acc[mt][nt] = (f32x4){0.f, 0.f, 0.f, 0.f};

    #pragma unroll
    for (int kt = 0; kt < 8; ++kt) {
        const half8 a0 = *(const half8*)&H16[l15][kt * 32 + qx];
        const half8 a1 = *(const half8*)&H16[16 + l15][kt * 32 + qx];
        #pragma unroll
        for (int nt = 0; nt < 4; ++nt) {
            const int ntg = w * 4 + nt;
            const half8 bf = *(const half8*)&w2p[((kt * 16 + ntg) * 64 + lane) * 8];
            acc[0][nt] = __builtin_amdgcn_mfma_f32_16x16x32_f16(a0, bf, acc[0][nt], 0, 0, 0);
            acc[1][nt] = __builtin_amdgcn_mfma_f32_16x16x32_f16(a1, bf, acc[1][nt], 0, 0, 0);
        }
    }
    __syncthreads();   // ALL A-reads of H16 complete before in-place store
    #pragma unroll
    for (int nt = 0; nt < 4; ++nt) {
        const int col  = w * 64 + nt * 16 + l15;
        const int colp = col ^ (quad << 3);
        const float bb = b2[col];
        #pragma unroll
        for (int mt = 0; mt < 2; ++mt)
            #pragma unroll
            for (int r = 0; r < 4; ++r)
                H16[16 * mt + 4 * quad + r][colp] = (_Float16)(acc[mt][nt][r] + bb);
    }
    __syncthreads();

    // ---- Phase 5: LN2 (no activation), packed, in place on H16 ----
    {
        H8u u0, u1, u2, u3;
        u0.v = *(const half8*)(hb + a0o);
        u1.v = *(const half8*)(hb + a1o);
        u2.v = *(const half8*)(hb + a2o);
        u3.v = *(const half8*)(hb + a3o);

        float s = 0.0f, s2 = 0.0f;
        stat8(u0, ones, s, s2); stat8(u1, ones, s, s2);
        stat8(u2, ones, s, s2); stat8(u3, ones, s, s2);
        #pragma unroll
        for (int off = 1; off < 8; off <<= 1) {
            s  += __shfl_xor(s, off, 64);
            s2 += __shfl_xor(s2, off, 64);
        }
        const float mu  = s * (1.0f / 256.0f);
        const float var = fmaf(s2, 1.0f / 256.0f, -mu * mu);
        const float rs  = __builtin_amdgcn_rsqf(var + 1e-5f);
        half2t rsh, nmuh;
        rsh[0]  = (_Float16)rs;    rsh[1]  = (_Float16)rs;
        nmuh[0] = (_Float16)(-mu); nmuh[1] = (_Float16)(-mu);

        H8u gA0, gA1, gB0, gB1, bA0, bA1, bB0, bB1;
        gA0.v = *(const half8*)&g2h[16 * p];        bA0.v = *(const half8*)&be2h[16 * p];
        gA1.v = *(const half8*)&g2h[16 * p + 8];    bA1.v = *(const half8*)&be2h[16 * p + 8];
        gB0.v = *(const half8*)&g2h[128 + 16 * p];  bB0.v = *(const half8*)&be2h[128 + 16 * p];
        gB1.v = *(const half8*)&g2h[136 + 16 * p];  bB1.v = *(const half8*)&be2h[136 + 16 * p];

        norm8(u0, gA0, bA0, rsh, nmuh);
        norm8(u1, gA1, bA1, rsh, nmuh);
        norm8(u2, gB0, bB0, rsh, nmuh);
        norm8(u3, gB1, bB1, rsh, nmuh);

        *(half8*)(hb + a0o) = u0.v;
        *(half8*)(hb + a1o) = u1.v;
        *(half8*)(hb + a2o) = u2.v;
        *(half8*)(hb + a3o) = u3.v;
    }
    __syncthreads();

    // ---- Phase 6: max over K, packed 2 cols/thread on waves 0-1 ----
    if (t < 128) {
        const _Float16* Hf = &H16[0][0];
        const int c = t >> 2;            // chunk index of cols (2t, 2t+1)
        const int o = (2 * t) & 7;       // offset within chunk
        half2t mx = *(const half2t*)(Hf + (c << 3) + o);
        #pragma unroll
        for (int r = 1; r < KN; ++r) {
            const half2t v = *(const half2t*)(Hf + r * HSTR + ((c ^ ((r >> 2) & 3)) << 3) + o);
            mx = __builtin_elementwise_max(mx, v);
        }
        float2 o2;
        o2.x = (float)mx[0];
        o2.y = (float)mx[1];
        *(float2*)&out0[(size_t)q * C + 2 * t] = o2;
    }
}

extern "C" void kernel_launch(void* const* d_in, const int* in_sizes, int n_in,
                              void* d_out, int out_size, void* d_ws, size_t ws_size,
                              hipStream_t stream) {
    const float* xyz = (const float*)d_in[0];
    const float* pf  = (const float*)d_in[1];
    const float* ctr = (const float*)d_in[2];
    const float* W1  = (const float*)d_in[3];
    const float* b1  = (const float*)d_in[4];
    const float* g1  = (const float*)d_in[5];
    const float* be1 = (const float*)d_in[6];
    const float* W2  = (const float*)d_in[7];
    const float* b2  = (const float*)d_in[8];
    const float* g2  = (const float*)d_in[9];
    const float* be2 = (const float*)d_in[10];

    float* out = (float*)d_out;
    _Float16* wp = (_Float16*)d_ws;

    prep_w_kernel<<<(96 * 256 + 65536) / 256, 256, 0, stream>>>(W1, W2, wp);
    encoder_fused<<<NQ, 256, 0, stream>>>(xyz, pf, ctr,
                                          b1, g1, be1, b2, g2, be2,
                                          wp, wp + W1P_ELEMS,
                                          out, out + PF_ELEMS);
}